// Round 9
// baseline (342.809 us; speedup 1.0000x reference)
//
#include <hip/hip_runtime.h>
#include <math.h>

#define B_SZ 2
#define SEQ  1024
#define DM   1024
#define DI   2048
#define NST  16
#define RNK  64
#define XPD  96            // RNK + 2*NST
#define M_TOT (B_SZ*SEQ)   // 2048
#define NC   64            // scan chunks
#define LC   (SEQ/NC)      // 16 steps per chunk
#define NCH  65536         // total chains = B_SZ*DI*NST

typedef unsigned short ushort_t;
typedef __attribute__((ext_vector_type(8))) short short8;   // 8 bf16 = 4 VGPRs
typedef __attribute__((ext_vector_type(4))) float f32x4;

#if __has_builtin(__builtin_amdgcn_exp2f)
#define EXP2F __builtin_amdgcn_exp2f
#else
#define EXP2F exp2f
#endif
#define LOG2E 1.44269504f

__device__ __forceinline__ ushort_t f2bf(float f) {
    unsigned u = __float_as_uint(f);
    u += 0x7fff + ((u >> 16) & 1);           // round-to-nearest-even
    return (ushort_t)(u >> 16);
}
__device__ __forceinline__ float bf2f(ushort_t v) {
    return __uint_as_float(((unsigned)v) << 16);
}

// ---------------------------------------------------------------------------
// One-shot prologue conversion (segmented by blockIdx):
//   x | inW_f | inW_b | outW_f (strided) | outW_b (strided) | xpW_f | xpW_b
//   blocks: 2048 | 4096 | 4096 | 2048 | 2048 | 192 | 192 = 14720
// ---------------------------------------------------------------------------
__global__ __launch_bounds__(256)
void convert_all(const float* __restrict__ x,
                 const float* __restrict__ inWf, const float* __restrict__ inWb,
                 const float* __restrict__ outWf, const float* __restrict__ outWb,
                 const float* __restrict__ xpWf, const float* __restrict__ xpWb,
                 ushort_t* __restrict__ xbf, ushort_t* __restrict__ inWcat,
                 ushort_t* __restrict__ outWcat, ushort_t* __restrict__ xpWcat)
{
    int bid = blockIdx.x;
    const float* src; ushort_t* dst; int rel; int strided = 0;
    if (bid < 2048)       { rel = bid;         src = x;     dst = xbf; }
    else if (bid < 6144)  { rel = bid - 2048;  src = inWf;  dst = inWcat; }
    else if (bid < 10240) { rel = bid - 6144;  src = inWb;  dst = inWcat + (size_t)2 * DI * DM; }
    else if (bid < 12288) { rel = bid - 10240; src = outWf; dst = outWcat;      strided = 1; }
    else if (bid < 14336) { rel = bid - 12288; src = outWb; dst = outWcat + DI; strided = 1; }
    else if (bid < 14528) { rel = bid - 14336; src = xpWf;  dst = xpWcat; }
    else                  { rel = bid - 14528; src = xpWb;  dst = xpWcat + (size_t)XPD * DI; }
    int i = rel * 256 + threadIdx.x;
    float4 v = ((const float4*)src)[i];
    ushort4 o;
    o.x = f2bf(v.x); o.y = f2bf(v.y); o.z = f2bf(v.z); o.w = f2bf(v.w);
    if (!strided) {
        ((ushort4*)dst)[i] = o;
    } else {
        int row = i >> 9;                 // rowLen4 = DI/4 = 512
        int c4  = (i - (row << 9)) << 2;
        *(ushort4*)(dst + (size_t)row * (2 * DI) + c4) = o;
    }
}

// ---------------------------------------------------------------------------
// Shared helper: async global->LDS 16B
// ---------------------------------------------------------------------------
__device__ __forceinline__ void load_lds16(const ushort_t* g, ushort_t* l) {
    __builtin_amdgcn_global_load_lds(
        (const __attribute__((address_space(1))) void*)g,
        (__attribute__((address_space(3))) void*)l, 16, 0, 0);
}

// ===========================================================================
// 256x256 8-phase bf16 NT GEMM (T2+T3+T4+T5 schedule, plain HIP).
//   xzall[M x GLD](bf16) = xbf[M x GK](bf16) * inWcat[8192 x GK]^T
//   8 waves (2M x 4N); 16 MFMA 16x16x32 per phase. BK=64, LDS 128 KiB dbuf.
//   GK=1024, GLD=8192, NT=16 compile-time; tile loop fully unrolled.
//
// Fully-rotated pre-read pipeline (once-per-tile counted vmcnt kept, moved
// P4 -> P3 and deepened 6 -> 4 so ALL of tile t+1 is resident at the P3->P4
// barrier — verified by FIFO accounting for steady state, t=0, and tail):
//   P1: rd b1(t)[4];            stage A1(t+1); BAR; lgkm(4)  [a0,b0 from
//       prev P4 drained; b1 flies]            MFMA (a0,b0);  BAR
//   P2: rd a1(t)[8];            stage A0(t+2); BAR; lgkm(8)  [b1 drained;
//       a1 flies]                              MFMA (a0,b1);  BAR
//   P3: no reads;               stage B0(t+2); BAR; lgkm(0);
//       MFMA (a1,b1); vmcnt(4|0); BAR         [tile t+1 fully resident]
//   P4: rd a0(t+1)[8]+b0(t+1)[4] (pre-read, dbuf b0); stage B1(t+2); BAR;
//       MFMA (a1,b0)  [no waits: operands long drained]; BAR
// WAR: every stage overwrite is >=2 barriers after the region's last
// drained read; every pre-read target vmcnt-drained + barrier-published.
// ===========================================================================
#define GK  1024
#define GLD 8192
#define GNT 16

__device__ __forceinline__ void stageHalf(const ushort_t* g, int grow0, int kt,
                                          ushort_t* lds, int w8, int l8, int gch)
{
    const ushort_t* p = g + (size_t)(grow0 + w8 + l8) * GK + (size_t)kt * 64 + (gch << 3);
    load_lds16(p,                   lds + w8 * 64);         // rows 0..63 of half
    load_lds16(p + (size_t)64 * GK, lds + (64 + w8) * 64);  // rows 64..127
}

__device__ __forceinline__ void rdA4(const ushort_t* buf, int rbase, int sw0, int sw1,
                                     short8 (&a)[4][2])
{
#pragma unroll
    for (int i = 0; i < 4; i++) {
        const ushort_t* p = buf + (size_t)(rbase + i * 16) * 64;
        a[i][0] = *(const short8*)(p + sw0);
        a[i][1] = *(const short8*)(p + sw1);
    }
}
__device__ __forceinline__ void rdB2(const ushort_t* buf, int rbase, int sw0, int sw1,
                                     short8 (&bb)[2][2])
{
#pragma unroll
    for (int j = 0; j < 2; j++) {
        const ushort_t* p = buf + (size_t)(rbase + j * 16) * 64;
        bb[j][0] = *(const short8*)(p + sw0);
        bb[j][1] = *(const short8*)(p + sw1);
    }
}
__device__ __forceinline__ void mm16(const short8 (&a)[4][2], const short8 (&bb)[2][2],
                                     f32x4 (&acc)[4][2])
{
#pragma unroll
    for (int i = 0; i < 4; i++)
#pragma unroll
        for (int j = 0; j < 2; j++) {
            acc[i][j] = __builtin_amdgcn_mfma_f32_16x16x32_bf16(a[i][0], bb[j][0], acc[i][j], 0, 0, 0);
            acc[i][j] = __builtin_amdgcn_mfma_f32_16x16x32_bf16(a[i][1], bb[j][1], acc[i][j], 0, 0, 0);
        }
}

#define BAR()        __builtin_amdgcn_s_barrier()
#define SCHEDB()     __builtin_amdgcn_sched_barrier(0)
#define PRIO1()      __builtin_amdgcn_s_setprio(1)
#define PRIO0()      __builtin_amdgcn_s_setprio(0)
#define WAIT_LGKM0() asm volatile("s_waitcnt lgkmcnt(0)" ::: "memory")
#define WAIT_LGKM4() asm volatile("s_waitcnt lgkmcnt(4)" ::: "memory")
#define WAIT_LGKM8() asm volatile("s_waitcnt lgkmcnt(8)" ::: "memory")
#define WAIT_VM4()   asm volatile("s_waitcnt vmcnt(4)"  ::: "memory")
#define WAIT_VM6()   asm volatile("s_waitcnt vmcnt(6)"  ::: "memory")
#define WAIT_VM0()   asm volatile("s_waitcnt vmcnt(0)"  ::: "memory")

__global__ __launch_bounds__(512, 2)
void gemm256_bf16(const ushort_t* __restrict__ A, const ushort_t* __restrict__ W,
                  ushort_t* __restrict__ D)
{
    __shared__ __align__(16) ushort_t As[2][256 * 64];   // 64 KiB
    __shared__ __align__(16) ushort_t Bs[2][256 * 64];   // 64 KiB

    const int t_   = threadIdx.x;
    const int lane = t_ & 63;
    const int wave = t_ >> 6;
    const int wrq  = wave >> 2;        // 0..1  (M quadrant row group)
    const int wcq  = wave & 3;         // 0..3  (N quadrant col group)
    const int lm   = lane & 15;
    const int w8   = wave << 3;
    const int l8   = lane >> 3;
    const int gch  = (lane & 7) ^ l8;                       // pre-swizzled global chunk
    const int sw0  = (((lane >> 4)    ) ^ (lane & 7)) << 3; // swizzled LDS chunk, kk=0
    const int sw1  = (((lane >> 4) + 4) ^ (lane & 7)) << 3; // kk=1

    const int m0 = blockIdx.y * 256;
    const int n0 = blockIdx.x * 256;

    const int rA0 = wrq * 64 + lm, rA1 = 128 + rA0;
    const int rB0 = wcq * 32 + lm, rB1 = 128 + rB0;

    f32x4 acc[2][2][4][2] = {};        // [ih][jh][i][j]
    short8 a0v[4][2], a1v[4][2], b1[2][2];
    short8 b0v[2][2][2];               // double-buffered b0 (toggled by t&1)

    // ---- prologue: tile0 full (4 halves) + tile1 A0,B0,B1 ----
    stageHalf(A, m0,       0, &As[0][0],        w8, l8, gch);
    stageHalf(A, m0 + 128, 0, &As[0][128 * 64], w8, l8, gch);
    stageHalf(W, n0,       0, &Bs[0][0],        w8, l8, gch);
    stageHalf(W, n0 + 128, 0, &Bs[0][128 * 64], w8, l8, gch);
    stageHalf(A, m0,       1, &As[1][0],        w8, l8, gch);
    stageHalf(W, n0,       1, &Bs[1][0],        w8, l8, gch);
    stageHalf(W, n0 + 128, 1, &Bs[1][128 * 64], w8, l8, gch);
    WAIT_VM6();                        // 14 issued, <=6 outstanding => tile0 landed
    BAR();
    // pre-read tile0 a0,b0 (they fly into tile0.P1; drained by its lgkm(4))
    rdA4(&As[0][0], rA0, sw0, sw1, a0v);
    rdB2(&Bs[0][0], rB0, sw0, sw1, b0v[0]);

#pragma unroll
    for (int t = 0; t < GNT; ++t) {
        const int b = t & 1;
        const ushort_t* Ab = &As[b][0];
        const ushort_t* Bb = &Bs[b][0];
        ushort_t* Abw = &As[b][0];
        ushort_t* Bbw = &Bs[b][0];
        ushort_t* Aow = &As[b ^ 1][0];
        const ushort_t* An = &As[b ^ 1][0];
        const ushort_t* Bn = &Bs[b ^ 1][0];
        short8 (&b0c)[2][2] = b0v[t & 1];
        short8 (&b0n)[2][2] = b0v[(t + 1) & 1];

        // ---- P1: MFMA (a0,b0); rd b1(t); stage A1(t+1) ----
        rdB2(Bb, rB1, sw0, sw1, b1);
        if (t + 1 < GNT) stageHalf(A, m0 + 128, t + 1, Aow + 128 * 64, w8, l8, gch); // A1(t+1)
        SCHEDB(); BAR(); WAIT_LGKM4(); SCHEDB();   // a0,b0 (12, issued prev P4) drained; b1 flies
        PRIO1(); mm16(a0v, b0c, acc[0][0]); PRIO0();
        SCHEDB(); BAR();

        // ---- P2: MFMA (a0,b1); rd a1(t); stage A0(t+2) ----
        rdA4(Ab, rA1, sw0, sw1, a1v);
        if (t + 2 < GNT) stageHalf(A, m0, t + 2, Abw, w8, l8, gch);                  // A0(t+2)
        SCHEDB(); BAR(); WAIT_LGKM8(); SCHEDB();   // b1 drained; a1 (8) flies
        PRIO1(); mm16(a0v, b1, acc[0][1]); PRIO0();
        SCHEDB(); BAR();

        // ---- P3: MFMA (a1,b1); stage B0(t+2); per-tile vmcnt ----
        if (t + 2 < GNT) stageHalf(W, n0, t + 2, Bbw, w8, l8, gch);                  // B0(t+2)
        SCHEDB(); BAR(); WAIT_LGKM0(); SCHEDB();   // a1 drained
        PRIO1(); mm16(a1v, b1, acc[1][1]); PRIO0();
        SCHEDB();
        if (t < GNT - 2) { WAIT_VM4(); } else { WAIT_VM0(); }  // tile t+1 fully resident
        BAR();

        // ---- P4: MFMA (a1,b0); pre-read a0(t+1),b0(t+1); stage B1(t+2) ----
        if (t + 1 < GNT) {
            rdA4(An, rA0, sw0, sw1, a0v);          // a0v dead since P2
            rdB2(Bn, rB0, sw0, sw1, b0n);          // other b0 buffer
        }
        if (t + 2 < GNT) stageHalf(W, n0 + 128, t + 2, Bbw + 128 * 64, w8, l8, gch); // B1(t+2)
        SCHEDB(); BAR(); SCHEDB();                 // no waits: a1,b0c long drained
        PRIO1(); mm16(a1v, b0c, acc[1][0]); PRIO0();
        SCHEDB(); BAR();
    }

    // ---- epilogue: C write (bf16) ----
#pragma unroll
    for (int ih = 0; ih < 2; ih++)
#pragma unroll
        for (int i = 0; i < 4; i++)
#pragma unroll
            for (int r = 0; r < 4; r++) {
                int m = m0 + ih * 128 + wrq * 64 + i * 16 + ((lane >> 4) << 2) + r;
#pragma unroll
                for (int jh = 0; jh < 2; jh++)
#pragma unroll
                    for (int j = 0; j < 2; j++) {
                        int n = n0 + jh * 128 + wcq * 32 + j * 16 + lm;
                        D[(size_t)m * GLD + n] = f2bf(acc[ih][jh][i][j][r]);
                    }
            }
}

// ---------------------------------------------------------------------------
// m97-style bf16 MFMA NT GEMM, 128x128 tile, BK=64, global_load_lds staging,
// XOR-swizzled unpadded LDS. OUT_BF16: D bf16 [M x ldD]; else fp32 partials.
// (GEMM3 split-K fp32-partials path)
// ---------------------------------------------------------------------------
template<bool OUT_BF16>
__global__ __launch_bounds__(256)
void gemm_gll(const ushort_t* __restrict__ A, const ushort_t* __restrict__ W,
              void* __restrict__ D, int M, int N, int K, int kLen, int ldD)
{
    __shared__ __align__(16) ushort_t As[128 * 64];
    __shared__ __align__(16) ushort_t Ws[128 * 64];
    const int t    = threadIdx.x;
    const int lane = t & 63;
    const int wave = t >> 6;
    const int wr   = (wave >> 1) * 64;
    const int wc   = (wave & 1) * 64;

    const int m0 = blockIdx.y * 128;
    const int n0 = blockIdx.x * 128;
    const int kStart = blockIdx.z * kLen;

    const int srow   = lane >> 3;
    const int gchunk = (lane & 7) ^ srow;

    f32x4 acc[4][4] = {};

    for (int k0 = kStart; k0 < kStart + kLen; k0 += 64) {
#pragma unroll
        for (int it = 0; it < 4; it++) {
            const int rb = wave * 32 + it * 8;
            load_lds16(A + (size_t)(m0 + rb + srow) * K + k0 + gchunk * 8,
                       As + rb * 64);
            load_lds16(W + (size_t)(n0 + rb + srow) * K + k0 + gchunk * 8,
                       Ws + rb * 64);
        }
        __syncthreads();
#pragma unroll
        for (int kk = 0; kk < 2; kk++) {
            const int kc = kk * 4 + (lane >> 4);
            short8 af[4], bf[4];
#pragma unroll
            for (int i = 0; i < 4; i++) {
                int r = wr + i * 16 + (lane & 15);
                af[i] = *(const short8*)(As + r * 64 + ((kc ^ (r & 7)) << 3));
            }
#pragma unroll
            for (int j = 0; j < 4; j++) {
                int r = wc + j * 16 + (lane & 15);
                bf[j] = *(const short8*)(Ws + r * 64 + ((kc ^ (r & 7)) << 3));
            }
#pragma unroll
            for (int i = 0; i < 4; i++)
#pragma unroll
                for (int j = 0; j < 4; j++)
                    acc[i][j] = __builtin_amdgcn_mfma_f32_16x16x32_bf16(
                        af[i], bf[j], acc[i][j], 0, 0, 0);
        }
        __syncthreads();
    }

    if (OUT_BF16) {
        ushort_t* Dp = (ushort_t*)D;
#pragma unroll
        for (int i = 0; i < 4; i++)
#pragma unroll
            for (int r = 0; r < 4; r++) {
                int m = m0 + wr + i * 16 + ((lane >> 4) << 2) + r;
#pragma unroll
                for (int j = 0; j < 4; j++) {
                    int n = n0 + wc + j * 16 + (lane & 15);
                    Dp[(size_t)m * ldD + n] = f2bf(acc[i][j][r]);
                }
            }
    } else {
        float* Dp = (float*)D + (size_t)blockIdx.z * M * ldD;
#pragma unroll
        for (int i = 0; i < 4; i++)
#pragma unroll
            for (int r = 0; r < 4; r++) {
                int m = m0 + wr + i * 16 + ((lane >> 4) << 2) + r;
#pragma unroll
                for (int j = 0; j < 4; j++) {
                    int n = n0 + wc + j * 16 + (lane & 15);
                    Dp[(size_t)m * ldD + n] = acc[i][j][r];
                }
            }
    }
}

// out = 0.5 * (P0 + P1 + P2 + P3)
__global__ __launch_bounds__(256)
void reduce4(const float* __restrict__ P, float* __restrict__ out)
{
    int i = blockIdx.x * 256 + threadIdx.x;
    const size_t S = (size_t)M_TOT * DM / 4;
    float4 a = ((const float4*)P)[i];
    float4 b = ((const float4*)P)[i + S];
    float4 c = ((const float4*)P)[i + 2 * S];
    float4 d = ((const float4*)P)[i + 3 * S];
    float4 o;
    o.x = 0.5f * (a.x + b.x + c.x + d.x);
    o.y = 0.5f * (a.y + b.y + c.y + d.y);
    o.z = 0.5f * (a.z + b.z + c.z + d.z);
    o.w = 0.5f * (a.w + b.w + c.w + d.w);
    ((float4*)out)[i] = o;
}

// ---------------------------------------------------------------------------
// GEMM2 both-dir split-K: grid (2, M/64, 16); z = dir*8 + kz.
// P[dir][kz] = ubf[dir] * xpW[dir]^T over K-slice. 64x64 tile, N=96 masked.
// ---------------------------------------------------------------------------
#define LDSP 72

__global__ __launch_bounds__(256)
void gemm2_splitk2(const ushort_t* __restrict__ ubf, const ushort_t* __restrict__ xpWcat,
                   float* __restrict__ P)
{
    const int dir = blockIdx.z >> 3;
    const int kz  = blockIdx.z & 7;
    const ushort_t* A = ubf + (size_t)dir * M_TOT * DI;
    const ushort_t* W = xpWcat + (size_t)dir * XPD * DI;
    const int K = DI, N = XPD;

    __shared__ __align__(16) ushort_t As[64 * LDSP];
    __shared__ __align__(16) ushort_t Ws[64 * LDSP];
    const int t    = threadIdx.x;
    const int lane = t & 63;
    const int wave = t >> 6;
    const int wr   = (wave >> 1) * 32;
    const int wc   = (wave & 1) * 32;

    f32x4 acc[2][2] = {};

    const int m0 = blockIdx.y * 64;
    const int n0 = blockIdx.x * 64;
    const int kStart = kz * (DI / 8);
    const int srow = t >> 3;
    const int scol = (t & 7) << 3;

    for (int k0 = kStart; k0 < kStart + DI / 8; k0 += 64) {
        {
            int r = srow;
            short8 v = *(const short8*)(A + (size_t)(m0 + r) * K + k0 + scol);
            *(short8*)(&As[r * LDSP + scol]) = v;
            int r2 = 32 + srow;
            short8 v2 = *(const short8*)(A + (size_t)(m0 + r2) * K + k0 + scol);
            *(short8*)(&As[r2 * LDSP + scol]) = v2;
            int wn = n0 + r;
            short8 wv = {};
            if (wn < N) wv = *(const short8*)(W + (size_t)wn * K + k0 + scol);
            *(short8*)(&Ws[r * LDSP + scol]) = wv;
            int wn2 = n0 + r2;
            short8 wv2 = {};
            if (wn2 < N) wv2 = *(const short8*)(W + (size_t)wn2 * K + k0 + scol);
            *(short8*)(&Ws[r2 * LDSP + scol]) = wv2;
        }
        __syncthreads();
#pragma unroll
        for (int kk = 0; kk < 2; kk++) {
            const int kcol = kk * 32 + ((lane >> 4) << 3);
            short8 af[2], bfr[2];
#pragma unroll
            for (int i = 0; i < 2; i++)
                af[i] = *(const short8*)(&As[(wr + i * 16 + (lane & 15)) * LDSP + kcol]);
#pragma unroll
            for (int j = 0; j < 2; j++)
                bfr[j] = *(const short8*)(&Ws[(wc + j * 16 + (lane & 15)) * LDSP + kcol]);
#pragma unroll
            for (int i = 0; i < 2; i++)
#pragma unroll
                for (int j = 0; j < 2; j++)
                    acc[i][j] = __builtin_amdgcn_mfma_f32_16x16x32_bf16(
                        af[i], bfr[j], acc[i][j], 0, 0, 0);
        }
        __syncthreads();
    }

    float* Pz = P + ((size_t)dir * 8 + kz) * M_TOT * XPD;
#pragma unroll
    for (int i = 0; i < 2; i++)
#pragma unroll
        for (int r = 0; r < 4; r++) {
            int m = m0 + wr + i * 16 + ((lane >> 4) << 2) + r;
#pragma unroll
            for (int j = 0; j < 2; j++) {
                int n = n0 + wc + j * 16 + (lane & 15);
                if (n < N) Pz[(size_t)m * XPD + n] = acc[i][j][r];
            }
        }
}

// xdbl[dir] = sum of 8 partials; grid 384 (192 per dir)
__global__ __launch_bounds__(256)
void xdbl_reduce2(const float* __restrict__ P, float* __restrict__ xdbl)
{
    int bid = blockIdx.x;
    int dir = bid >= 192;
    int i = (bid - dir * 192) * 256 + threadIdx.x;   // float4 over M*XPD/4
    const size_t S = (size_t)M_TOT * XPD / 4;
    const float4* Pd = (const float4*)(P + (size_t)dir * 8 * M_TOT * XPD);
    float4 s = Pd[i];
#pragma unroll
    for (int z = 1; z < 8; z++) {
        float4 v = Pd[i + z * S];
        s.x += v.x; s.y += v.y; s.z += v.z; s.w += v.w;
    }
    ((float4*)(xdbl + (size_t)dir * M_TOT * XPD))[i] = s;
}

// ---------------------------------------------------------------------------
// delta[dir] = softplus(dt * dtW[dir]^T + dtB[dir]) -> bf16 [M x DI]
// grid (DI/64, M/64, 2); single-K-tile MFMA GEMM.
// ---------------------------------------------------------------------------
__global__ __launch_bounds__(256)
void delta_gemm2(const float* __restrict__ xdbl,
                 const float* __restrict__ dtWf, const float* __restrict__ dtWb,
                 const float* __restrict__ dtBf, const float* __restrict__ dtBb,
                 ushort_t* __restrict__ deltab)
{
    const int dir = blockIdx.z;
    const float* xd  = xdbl + (size_t)dir * M_TOT * XPD;
    const float* dtW = dir ? dtWb : dtWf;
    const float* dtB = dir ? dtBb : dtBf;
    ushort_t* delta  = deltab + (size_t)dir * M_TOT * DI;

    __shared__ __align__(16) ushort_t As[64 * LDSP];
    __shared__ __align__(16) ushort_t Ws[64 * LDSP];
    const int t    = threadIdx.x;
    const int lane = t & 63;
    const int wave = t >> 6;
    const int wr   = (wave >> 1) * 32;
    const int wc   = (wave & 1) * 32;

    const int m0 = blockIdx.y * 64;
    const int n0 = blockIdx.x * 64;
    const int srow = t >> 2;            // 0..63
    const int scol = (t & 3) << 4;      // 0,16,32,48

    {
        const float* ap = xd  + (size_t)(m0 + srow) * XPD + scol;
        const float* wp = dtW + (size_t)(n0 + srow) * RNK + scol;
        float4 a[4], w[4];
#pragma unroll
        for (int q = 0; q < 4; q++) { a[q] = ((const float4*)ap)[q]; w[q] = ((const float4*)wp)[q]; }
        __align__(16) ushort_t at[16], wt[16];
#pragma unroll
        for (int q = 0; q < 16; q++) {
            at[q] = f2bf(((const float*)a)[q]);
            wt[q] = f2bf(((const float*)w)[q]);
        }
        *(short8*)(&As[srow * LDSP + scol])     = *(const short8*)(at);
        *(short8*)(&As[srow * LDSP + scol + 8]) = *(const short8*)(at + 8);
        *(short8*)(&Ws[srow * LDSP + scol])     = *(const short8*)(wt);
        *(short8*)(&Ws[srow * LDSP + scol + 8]) = *(const short8*)(wt + 8);
    }
    __syncthreads();

    f32x4 acc[2][2] = {};
#pragma unroll
    for (int kk = 0; kk < 2; kk++) {
        const int kcol = kk * 32 + ((lane >> 4) << 3);
        short8 af[2], bfr[2];
#pragma unroll
        for (int i = 0; i < 2; i++)
            af[i] = *(const short8*)(&As[(wr + i * 16 + (lane & 15)) * LDSP + kcol]);
#pragma unroll
        for (int j = 0; j < 2; j++)
            bfr[j] = *(const short8*)(&Ws[(wc + j * 16 + (lane & 15)) * LDSP + kcol]);
#pragma unroll
        for (int i = 0; i < 2; i++)
#pragma unroll
            for (int j = 0; j < 2; j++)
                acc[i][j] = __builtin_amdgcn_mfma_f32_16x16x32_bf16(
                    af[i], bfr[j], acc[i][j], 0, 0, 0);
    }

#pragma unroll
    for (int j = 0; j < 2; j++) {
        int n = n0 + wc + j * 16 + (lane & 15);
        float bn = dtB[n];
#pragma unroll
        for (int i = 0; i < 2; i++) {
#pragma unroll
            for (int r = 0; r < 4; r++) {
                int m = m0 + wr + i * 16 + ((lane >> 4) << 2) + r;
                float v = acc[i][j][r] + bn;
                float sp = (v > 20.f) ? v : log1pf(__expf(v));
                delta[(size_t)m * DI + n] = f2bf(sp);
            }
        }
    }
}

// ---------------------------------------------------------------------------
// Depthwise conv(4) + bias + SiLU, both dirs: grid 8192 (4096 per dir).
// dir=0 causal, dir=1 anti-causal (natural order). -> ubf[dir] bf16.
// ---------------------------------------------------------------------------
__global__ __launch_bounds__(256)
void conv_silu2(const ushort_t* __restrict__ xzall,
                const float* __restrict__ convWf, const float* __restrict__ convWb,
                const float* __restrict__ convBf, const float* __restrict__ convBb,
                ushort_t* __restrict__ ubf)
{
    int bid = blockIdx.x;
    int dir = bid >> 12;                          // 4096 blocks per dir
    int idx = (bid & 4095) * 256 + threadIdx.x;   // over M_TOT*DI/4
    const float* convW = dir ? convWb : convWf;
    const float* convB = dir ? convBb : convBf;
    int di  = (idx & (DI / 4 - 1)) << 2;
    int m   = idx >> 9;
    int b   = m >> 10, l = m & (SEQ - 1);
    const ushort_t* xb = xzall + (size_t)b * SEQ * (4 * DI) + dir * (2 * DI) + di;

    float wv[4][4];
#pragma unroll
    for (int c = 0; c < 4; c++) {
        float4 w = *(const float4*)(convW + (di + c) * 4);
        wv[c][0] = w.x; wv[c][1] = w.y; wv[c][2] = w.z; wv[c][3] = w.w;
    }
    float4 cb = *(const float4*)(convB + di);
    float acc[4] = {cb.x, cb.y, cb.z, cb.w};
#pragma unroll
    for (int j = 0; j < 4; j++) {
        int srcl = dir ? (l + 3 - j) : (l - 3 + j);
        if ((unsigned)srcl < SEQ) {
            ushort4 xv = *(const ushort4*)(xb + (size_t)srcl * (4 * DI));
            acc[0] += wv[0][j] * bf2f(xv.x);
            acc[1] += wv[1][j] * bf2f(xv.y);
            acc[2] += wv[2][j] * bf2f(xv.z);
            acc[3] += wv[3][j] * bf2f(xv.w);
        }
    }
    ushort4 o;
    o.x = f2bf(acc[0] / (1.f + __expf(-acc[0])));
    o.y = f2bf(acc[1] / (1.f + __expf(-acc[1])));
    o.z = f2bf(acc[2] / (1.f + __expf(-acc[2])));
    o.w = f2bf(acc[3] / (1.f + __expf(-acc[3])));
    *(ushort4*)(ubf + (size_t)dir * M_TOT * DI + (size_t)m * DI + di) = o;
}

// ---------------------------------------------------------------------------
// Chunked selective scan, both dirs (lane = d, 16 states/lane).
// NC=64 chunks of LC=16: grid 2048 = 1024/dir.
// Within dir: dg = blk&7, c = (blk>>3)&63, b = blk>>6 (per-dir).
// Chunk boundary states stored bf16 (fits the dead inWcat overlay).
// ---------------------------------------------------------------------------
__global__ __launch_bounds__(256)
void scan_pass1_2(const ushort_t* __restrict__ deltab, const ushort_t* __restrict__ ubf,
                  const float* __restrict__ xdbl,
                  const float* __restrict__ Alogf, const float* __restrict__ Alogb,
                  ushort_t* __restrict__ Sb, float* __restrict__ SD)
{
    int tid = threadIdx.x, lane = tid & 63, wv = tid >> 6;
    int blk = blockIdx.x;
    int dir = blk >> 10;
    blk &= 1023;
    int dg = blk & 7;
    int bc = blk >> 3;
    int c  = bc & (NC - 1);
    int b  = bc >> 6;
    int d  = (dg * 4 + wv) * 64 + lane;
    int t0 = dir ? (SEQ - 1 - c * LC) : (c * LC);
    int rs = dir ? -1 : 1;

    const float* Alog = dir ? Alogb : Alogf;
    const ushort_t* dl_p = deltab + (size_t)dir * M_TOT * DI;
    const ushort_t* u_p  = ubf    + (size_t)dir * M_TOT * DI;
    const float*    xd   = xdbl   + (size_t)dir * M_TOT * XPD;
    ushort_t* Sbd = Sb + (size_t)dir * NC * NCH;
    float* SDd = SD + (size_t)dir * NC * B_SZ * DI;

    float ac2[NST];
#pragma unroll
    for (int q = 0; q < 4; q++) {
        float4 al = *(const float4*)(Alog + (size_t)d * NST + q * 4);
        ac2[q * 4 + 0] = -__expf(al.x) * LOG2E;
        ac2[q * 4 + 1] = -__expf(al.y) * LOG2E;
        ac2[q * 4 + 2] = -__expf(al.z) * LOG2E;
        ac2[q * 4 + 3] = -__expf(al.w) * LOG2E;
    }
    float h[NST];
#pragma unroll
    for (int n = 0; n < NST; n++) h[n] = 0.f;
    float sumD = 0.f;

#pragma unroll 4
    for (int l = 0; l < LC; l++) {
        int t = t0 + rs * l;
        size_t row = (size_t)b * SEQ + t;
        float dl = bf2f(dl_p[row * DI + d]);
        float uv = bf2f(u_p[row * DI + d]);
        const float* xr = xd + row * XPD + RNK;
        float4 Bv[4];
#pragma unroll
        for (int q = 0; q < 4; q++) Bv[q] = *(const float4*)(xr + q * 4);
        float dlu = dl * uv;
        sumD += dl;
#pragma unroll
        for (int n = 0; n < NST; n++) {
            float dA = EXP2F(dl * ac2[n]);
            h[n] = h[n] * dA + dlu * ((const float*)Bv)[n];
        }
    }

    size_t o = (size_t)c * NCH + ((size_t)b * DI + d) * NST;
#pragma unroll
    for (int q = 0; q < 4; q++) {
        ushort4 pk;
        pk.x = f2bf(h[q * 4 + 0]);
        pk.y = f2bf(h[q * 4 + 1]);
        pk.z = f2bf(h[q * 4 + 2]);
        pk.w = f2bf(h[q * 4 + 3]);
        *(ushort4*)(Sbd + o + q * 4) = pk;
    }
    SDd[(size_t)c * (B_SZ * DI) + b * DI + d] = sumD;
}

__global__ __launch_bounds__(256)
void scan_combine2(ushort_t* __restrict__ Sb, const float* __restrict__ SD,
                   const float* __restrict__ Alogf, const float* __restrict__ Alogb)
{
    int gid = blockIdx.x * 256 + threadIdx.x;   // 0 .. 2*NCH-1
    int dir = gid >= NCH;
    int i = gid - dir * NCH;
    int n = i & 15;
    int d = (i >> 4) & (DI - 1);
    int b = i >> 15;
    const float* Alog = dir ? Alogb : Alogf;
    ushort_t* Sbd = Sb + (size_t)dir * NC * NCH;
    const float* SDd = SD + (size_t)dir * NC * B_SZ * DI;
    float ac2 = -__expf(Alog[(size_t)d * NST + n]) * LOG2E;
    float h = 0.f;
#pragma unroll
    for (int c = 0; c < NC; c++) {
        float s = bf2f(Sbd[(size_t)c * NCH + i]);
        float p = EXP2F(ac2 * SDd[(size_t)c * (B_SZ * DI) + b * DI + d]);
        Sbd[(size_t)c * NCH + i] = f2bf(h);
        h = s + p * h;
    }
}

__global__ __launch_bounds__(256)
void scan_pass2_2(const ushort_t* __restrict__ deltab, const ushort_t* __restrict__ ubf,
                  const float* __restrict__ xdbl, const ushort_t* __restrict__ xzall,
                  const float* __restrict__ Alogf, const float* __restrict__ Alogb,
                  const float* __restrict__ Dpf, const float* __restrict__ Dpb,
                  const ushort_t* __restrict__ Hinit, ushort_t* __restrict__ ybf)
{
    int tid = threadIdx.x, lane = tid & 63, wv = tid >> 6;
    int blk = blockIdx.x;
    int dir = blk >> 10;
    blk &= 1023;
    int dg = blk & 7;
    int bc = blk >> 3;
    int c  = bc & (NC - 1);
    int b  = bc >> 6;
    int d  = (dg * 4 + wv) * 64 + lane;
    int t0 = dir ? (SEQ - 1 - c * LC) : (c * LC);
    int rs = dir ? -1 : 1;

    const float* Alog = dir ? Alogb : Alogf;
    const float* Dpp  = dir ? Dpb : Dpf;
    const ushort_t* dl_p = deltab + (size_t)dir * M_TOT * DI;
    const ushort_t* u_p  = ubf    + (size_t)dir * M_TOT * DI;
    const float*    xd   = xdbl   + (size_t)dir * M_TOT * XPD;
    const ushort_t* Hin  = Hinit  + (size_t)dir * NC * NCH;

    float ac2[NST];
#pragma unroll
    for (int q = 0; q < 4; q++) {
        float4 al = *(const float4*)(Alog + (size_t)d * NST + q * 4);
        ac2[q * 4 + 0] = -__expf(al.x) * LOG2E;
        ac2[q * 4 + 1] = -__expf(al.y) * LOG2E;
        ac2[q * 4 + 2] = -__expf(al.z) * LOG2E;
        ac2[q * 4 + 3] = -__expf(al.w) * LOG2E;
    }
    float dp = Dpp[d];
    float h[NST];
    {
        size_t o = (size_t)c * NCH + ((size_t)b * DI + d) * NST;
#pragma unroll
        for (int q = 0; q < 4; q++) {
            ushort4 hv = *(const ushort4*)(Hin + o + q * 4);
            h[q*4]   = bf2f(hv.x);
            h[q*4+1] = bf2f(hv.y);
            h[q*4+2] = bf2f(hv.z);
            h[q*4+3] = bf2f(hv.w);
        }
    }

#pragma unroll 4
    for (int l = 0; l < LC; l++) {
        int t = t0 + rs * l;
        size_t row = (size_t)b * SEQ + t;
        float dl = bf2f(dl_p[row * DI + d]);
        float uv = bf2f(u_p[row * DI + d]);
        const float* xr = xd + row * XPD + RNK;
        float4 Bv[4], Cv[4];
#pragma unroll
        for (int q = 0; q < 4; q++) {
            Bv[q] = *(const float4*)(xr + q * 4);
            Cv[q] = *(const float4*)(xr + NST + q * 4);
        }
        float dlu = dl * uv;
        float y = 0.f;
#pragma unroll
        for (int n = 0; n < NST; n++) {
            float dA = EXP2F(dl * ac2[n]);
            h[n] = h[n] * dA + dlu * ((const float*)Bv)[n];
            y += h[n] * ((const float*)Cv)[n];
        }
        float z = bf2f(xzall[row * (4 * DI) + dir * (2 * DI) + DI + d]);
        float yv = (y + uv * dp) * (z / (1.f + __expf(-z)));
        ybf[row * (2 * DI) + dir * DI + d] = f2bf(yv);
    }
}

// ---------------------------------------------------------------------------
extern "C" void kernel_launch(void* const* d_in, const int* in_sizes, int n_in,
                              void* d_out, int out_size, void* d_ws, size_t ws_size,
                              hipStream_t stream)
{
    char* wsb = (char*)d_ws;

    // layout (bytes), total 115,605,504:
    ushort_t* xzall  = (ushort_t*)wsb;                 // 33,554,432 [M x 8192] bf16
    ushort_t* ybf    = (ushort_t*)(wsb + 33554432);    // 16,777,216 [M x 2*DI] bf16
    ushort_t* inWcat = (ushort_t*)(wsb + 50331648);    // 16,777,216
    ushort_t* outWcat= (ushort_t*)(wsb + 67108864);    //  8,388,608 [DM x 2*DI] bf16
    ushort_t* xbf    = (ushort_t*)(wsb + 75497472);    //  4,194,304 [M x DM] bf16
    ushort_t* xpWcat = (ushort_t*)(wsb + 79691776);    //    786,432 [2][XPD x DI] bf16
    ushort_t* ubf    = (ushort_t*)(wsb + 80478208);    // 16,777,216 [2][M x DI] bf16
    ushort_t* deltab = (ushort_t*)(wsb + 97255424);    // 16,777,216 [2][M x DI] bf16
    float*    xdbl   = (float*)(wsb + 114032640);      //  1,572,864 [2][M x XPD] fp32

    // overlays (dead regions):
    ushort_t* Sb   = (ushort_t*)inWcat;                // 16,777,216 [2][NC=64 x NCH] bf16 (after GEMM1)
    float* SD    = (float*)xbf;                        //  2,097,152 [2][NC x B*DI]   (after GEMM1)
    float* part2 = (float*)deltab;                     // 12,582,912 [2][8 x M x XPD] (pre-delta)
    float* part4 = (float*)xzall;                      // 33,554,432 [4 x M x DM] fp32 (after scans)

    float* out = (float*)d_out;
    dim3 blk(256);

    // 1. prologue conversions (single dispatch)
    convert_all<<<14720, blk, 0, stream>>>(
        (const float*)d_in[0], (const float*)d_in[1], (const float*)d_in[10],
        (const float*)d_in[9], (const float*)d_in[18],
        (const float*)d_in[4], (const float*)d_in[13],
        xbf, inWcat, outWcat, xpWcat);

    // 2. xzall = x * [inW_f; inW_b]^T   [2048 x 8192], K=1024, bf16 out
    //    256x256 schedule, fully-rotated pre-reads + counted vmcnt@P3
    gemm256_bf16<<<dim3(8192 / 256, M_TOT / 256), dim3(512), 0, stream>>>(
        xbf, inWcat, xzall);

    // 3. u = silu(conv(xi)), both dirs (4096 blocks per dir)
    conv_silu2<<<8192, blk, 0, stream>>>(xzall,
        (const float*)d_in[2], (const float*)d_in[11],
        (const float*)d_in[3], (const float*)d_in[12], ubf);

    // 4. xdbl partials, both dirs, split-K=8
    gemm2_splitk2<<<dim3(2, M_TOT / 64, 16), blk, 0, stream>>>(ubf, xpWcat, part2);

    // 5. xdbl = sum partials, both dirs
    xdbl_reduce2<<<384, blk, 0, stream>>>(part2, xdbl);

    // 6. delta = softplus(dt*dtW^T + dtB) -> bf16, both dirs
    delta_gemm2<<<dim3(DI / 64, M_TOT / 64, 2), blk, 0, stream>>>(
        xdbl, (const float*)d_in[5], (const float*)d_in[14],
        (const float*)d_in[6], (const float*)d_in[15], deltab);

    // 7-9. chunked exact scan (NC=64 chunks of LC=16), both dirs
    scan_pass1_2<<<2048, blk, 0, stream>>>(deltab, ubf, xdbl,
        (const float*)d_in[7], (const float*)d_in[16], Sb, SD);
    scan_combine2<<<2 * NCH / 256, blk, 0, stream>>>(Sb, SD,
        (const float*)d_in[7], (const float*)d_in[16]);
    scan_pass2_2<<<2048, blk, 0, stream>>>(deltab, ubf, xdbl, xzall,
        (const float*)d_in[7], (const float*)d_in[16],
        (const float*)d_in[8], (const float*)d_in[17], Sb, ybf);

    // 10. out = 0.5 * [y_f | y_b] * [outW_f | outW_b]^T : K=4096, splitK=4
    gemm_gll<false><<<dim3(DM / 128, M_TOT / 128, 4), blk, 0, stream>>>(
        ybf, outWcat, part4, M_TOT, DM, 2 * DI, DI / 2, DM);

    // 11. final reduce
    reduce4<<<(M_TOT * DM / 4) / 256, blk, 0, stream>>>(part4, out);
}

// Round 11
// 336.652 us; speedup vs baseline: 1.0183x; 1.0183x over previous
//
#include <hip/hip_runtime.h>
#include <math.h>

#define B_SZ 2
#define SEQ  1024
#define DM   1024
#define DI   2048
#define NST  16
#define RNK  64
#define XPD  96            // RNK + 2*NST
#define M_TOT (B_SZ*SEQ)   // 2048
#define NC   64            // scan chunks
#define LC   (SEQ/NC)      // 16 steps per chunk
#define NCH  65536         // total chains = B_SZ*DI*NST

typedef unsigned short ushort_t;
typedef __attribute__((ext_vector_type(8))) short short8;   // 8 bf16 = 4 VGPRs
typedef __attribute__((ext_vector_type(4))) float f32x4;

#if __has_builtin(__builtin_amdgcn_exp2f)
#define EXP2F __builtin_amdgcn_exp2f
#else
#define EXP2F exp2f
#endif
#define LOG2E 1.44269504f

__device__ __forceinline__ ushort_t f2bf(float f) {
    unsigned u = __float_as_uint(f);
    u += 0x7fff + ((u >> 16) & 1);           // round-to-nearest-even
    return (ushort_t)(u >> 16);
}
__device__ __forceinline__ float bf2f(ushort_t v) {
    return __uint_as_float(((unsigned)v) << 16);
}

// ---------------------------------------------------------------------------
// One-shot prologue conversion (segmented by blockIdx):
//   x | inW_f | inW_b | outW_f (strided) | outW_b (strided) | xpW_f | xpW_b
//   blocks: 2048 | 4096 | 4096 | 2048 | 2048 | 192 | 192 = 14720
// ---------------------------------------------------------------------------
__global__ __launch_bounds__(256)
void convert_all(const float* __restrict__ x,
                 const float* __restrict__ inWf, const float* __restrict__ inWb,
                 const float* __restrict__ outWf, const float* __restrict__ outWb,
                 const float* __restrict__ xpWf, const float* __restrict__ xpWb,
                 ushort_t* __restrict__ xbf, ushort_t* __restrict__ inWcat,
                 ushort_t* __restrict__ outWcat, ushort_t* __restrict__ xpWcat)
{
    int bid = blockIdx.x;
    const float* src; ushort_t* dst; int rel; int strided = 0;
    if (bid < 2048)       { rel = bid;         src = x;     dst = xbf; }
    else if (bid < 6144)  { rel = bid - 2048;  src = inWf;  dst = inWcat; }
    else if (bid < 10240) { rel = bid - 6144;  src = inWb;  dst = inWcat + (size_t)2 * DI * DM; }
    else if (bid < 12288) { rel = bid - 10240; src = outWf; dst = outWcat;      strided = 1; }
    else if (bid < 14336) { rel = bid - 12288; src = outWb; dst = outWcat + DI; strided = 1; }
    else if (bid < 14528) { rel = bid - 14336; src = xpWf;  dst = xpWcat; }
    else                  { rel = bid - 14528; src = xpWb;  dst = xpWcat + (size_t)XPD * DI; }
    int i = rel * 256 + threadIdx.x;
    float4 v = ((const float4*)src)[i];
    ushort4 o;
    o.x = f2bf(v.x); o.y = f2bf(v.y); o.z = f2bf(v.z); o.w = f2bf(v.w);
    if (!strided) {
        ((ushort4*)dst)[i] = o;
    } else {
        int row = i >> 9;                 // rowLen4 = DI/4 = 512
        int c4  = (i - (row << 9)) << 2;
        *(ushort4*)(dst + (size_t)row * (2 * DI) + c4) = o;
    }
}

// ---------------------------------------------------------------------------
// Shared helper: async global->LDS 16B
// ---------------------------------------------------------------------------
__device__ __forceinline__ void load_lds16(const ushort_t* g, ushort_t* l) {
    __builtin_amdgcn_global_load_lds(
        (const __attribute__((address_space(1))) void*)g,
        (__attribute__((address_space(3))) void*)l, 16, 0, 0);
}

// ===========================================================================
// 256x256 8-phase bf16 NT GEMM (T2+T3+T4+T5 schedule, plain HIP).
//   xzall[M x GLD](bf16) = xbf[M x GK](bf16) * inWcat[8192 x GK]^T
//   8 waves (2M x 4N); 16 MFMA 16x16x32 per phase. BK=64, LDS 128 KiB dbuf.
//   GK=1024, GLD=8192, NT=16 compile-time; tile loop fully unrolled so all
//   stage predicates fold and addresses are compile-time offsets.
// Phase schedule per tile t (quads (A0,B0),(A0,B1),(A1,B1),(A1,B0)):
//   P1: rd A0+B0 (12 ds_read); stage A1(t+1)
//   P2: rd B1 (4);             stage A0(t+2)
//   P3: rd A1 (8);             stage B0(t+2)
//   P4: no reads;              stage B1(t+2); vmcnt(6) (counted, never 0)
// At 790 TF this is ~93% of the documented same-shape (K=1024) full-stack
// reference (m248: 848 TF); three alternative schedules measured 0 to -23%.
// ===========================================================================
#define GK  1024
#define GLD 8192
#define GNT 16

__device__ __forceinline__ void stageHalf(const ushort_t* g, int grow0, int kt,
                                          ushort_t* lds, int w8, int l8, int gch)
{
    const ushort_t* p = g + (size_t)(grow0 + w8 + l8) * GK + (size_t)kt * 64 + (gch << 3);
    load_lds16(p,                   lds + w8 * 64);         // rows 0..63 of half
    load_lds16(p + (size_t)64 * GK, lds + (64 + w8) * 64);  // rows 64..127
}

__device__ __forceinline__ void rdA4(const ushort_t* buf, int rbase, int sw0, int sw1,
                                     short8 (&a)[4][2])
{
#pragma unroll
    for (int i = 0; i < 4; i++) {
        const ushort_t* p = buf + (size_t)(rbase + i * 16) * 64;
        a[i][0] = *(const short8*)(p + sw0);
        a[i][1] = *(const short8*)(p + sw1);
    }
}
__device__ __forceinline__ void rdB2(const ushort_t* buf, int rbase, int sw0, int sw1,
                                     short8 (&bb)[2][2])
{
#pragma unroll
    for (int j = 0; j < 2; j++) {
        const ushort_t* p = buf + (size_t)(rbase + j * 16) * 64;
        bb[j][0] = *(const short8*)(p + sw0);
        bb[j][1] = *(const short8*)(p + sw1);
    }
}
__device__ __forceinline__ void mm16(const short8 (&a)[4][2], const short8 (&bb)[2][2],
                                     f32x4 (&acc)[4][2])
{
#pragma unroll
    for (int i = 0; i < 4; i++)
#pragma unroll
        for (int j = 0; j < 2; j++) {
            acc[i][j] = __builtin_amdgcn_mfma_f32_16x16x32_bf16(a[i][0], bb[j][0], acc[i][j], 0, 0, 0);
            acc[i][j] = __builtin_amdgcn_mfma_f32_16x16x32_bf16(a[i][1], bb[j][1], acc[i][j], 0, 0, 0);
        }
}

#define BAR()        __builtin_amdgcn_s_barrier()
#define SCHEDB()     __builtin_amdgcn_sched_barrier(0)
#define PRIO1()      __builtin_amdgcn_s_setprio(1)
#define PRIO0()      __builtin_amdgcn_s_setprio(0)
#define WAIT_LGKM0() asm volatile("s_waitcnt lgkmcnt(0)" ::: "memory")
#define WAIT_VM6()   asm volatile("s_waitcnt vmcnt(6)"  ::: "memory")
#define WAIT_VM0()   asm volatile("s_waitcnt vmcnt(0)"  ::: "memory")

__global__ __launch_bounds__(512, 2)
void gemm256_bf16(const ushort_t* __restrict__ A, const ushort_t* __restrict__ W,
                  ushort_t* __restrict__ D)
{
    __shared__ __align__(16) ushort_t As[2][256 * 64];   // 64 KiB
    __shared__ __align__(16) ushort_t Bs[2][256 * 64];   // 64 KiB

    const int t_   = threadIdx.x;
    const int lane = t_ & 63;
    const int wave = t_ >> 6;
    const int wrq  = wave >> 2;        // 0..1  (M quadrant row group)
    const int wcq  = wave & 3;         // 0..3  (N quadrant col group)
    const int lm   = lane & 15;
    const int w8   = wave << 3;
    const int l8   = lane >> 3;
    const int gch  = (lane & 7) ^ l8;                       // pre-swizzled global chunk
    const int sw0  = (((lane >> 4)    ) ^ (lane & 7)) << 3; // swizzled LDS chunk, kk=0
    const int sw1  = (((lane >> 4) + 4) ^ (lane & 7)) << 3; // kk=1

    const int m0 = blockIdx.y * 256;
    const int n0 = blockIdx.x * 256;

    const int rA0 = wrq * 64 + lm, rA1 = 128 + rA0;
    const int rB0 = wcq * 32 + lm, rB1 = 128 + rB0;

    f32x4 acc[2][2][4][2] = {};        // [ih][jh][i][j]
    short8 a[4][2], b0[2][2], b1[2][2];

    // ---- prologue: tile0 full (4 halves) + tile1 A0,B0,B1 ----
    stageHalf(A, m0,       0, &As[0][0],        w8, l8, gch);
    stageHalf(A, m0 + 128, 0, &As[0][128 * 64], w8, l8, gch);
    stageHalf(W, n0,       0, &Bs[0][0],        w8, l8, gch);
    stageHalf(W, n0 + 128, 0, &Bs[0][128 * 64], w8, l8, gch);
    stageHalf(A, m0,       1, &As[1][0],        w8, l8, gch);
    stageHalf(W, n0,       1, &Bs[1][0],        w8, l8, gch);
    stageHalf(W, n0 + 128, 1, &Bs[1][128 * 64], w8, l8, gch);
    WAIT_VM6();                        // 14 issued, <=6 outstanding => tile0 landed
    BAR();

#pragma unroll
    for (int t = 0; t < GNT; ++t) {
        const int b = t & 1;
        const ushort_t* Ab = &As[b][0];
        const ushort_t* Bb = &Bs[b][0];
        ushort_t* Abw = &As[b][0];
        ushort_t* Bbw = &Bs[b][0];
        ushort_t* Aow = &As[b ^ 1][0];

        // ---- P1: quad (A0,B0) ----
        rdA4(Ab, rA0, sw0, sw1, a);
        rdB2(Bb, rB0, sw0, sw1, b0);
        if (t + 1 < GNT) stageHalf(A, m0 + 128, t + 1, Aow + 128 * 64, w8, l8, gch); // A1(t+1)
        SCHEDB(); BAR(); WAIT_LGKM0(); SCHEDB();
        PRIO1(); mm16(a, b0, acc[0][0]); PRIO0();
        SCHEDB(); BAR();

        // ---- P2: quad (A0,B1) ----
        rdB2(Bb, rB1, sw0, sw1, b1);
        if (t + 2 < GNT) stageHalf(A, m0, t + 2, Abw, w8, l8, gch);                  // A0(t+2)
        SCHEDB(); BAR(); WAIT_LGKM0(); SCHEDB();
        PRIO1(); mm16(a, b1, acc[0][1]); PRIO0();
        SCHEDB(); BAR();

        // ---- P3: quad (A1,B1) ----
        rdA4(Ab, rA1, sw0, sw1, a);
        if (t + 2 < GNT) stageHalf(W, n0, t + 2, Bbw, w8, l8, gch);                  // B0(t+2)
        SCHEDB(); BAR(); WAIT_LGKM0(); SCHEDB();
        PRIO1(); mm16(a, b1, acc[1][1]); PRIO0();
        SCHEDB(); BAR();

        // ---- P4: quad (A1,B0), no new ds_reads ----
        if (t + 2 < GNT) stageHalf(W, n0 + 128, t + 2, Bbw + 128 * 64, w8, l8, gch); // B1(t+2)
        SCHEDB(); BAR();
        PRIO1(); mm16(a, b0, acc[1][0]); PRIO0();
        SCHEDB();
        if (t < GNT - 2) { WAIT_VM6(); } else { WAIT_VM0(); }   // counted; drain only at tail
        BAR();
    }

    // ---- epilogue: C write (bf16) ----
#pragma unroll
    for (int ih = 0; ih < 2; ih++)
#pragma unroll
        for (int i = 0; i < 4; i++)
#pragma unroll
            for (int r = 0; r < 4; r++) {
                int m = m0 + ih * 128 + wrq * 64 + i * 16 + ((lane >> 4) << 2) + r;
#pragma unroll
                for (int jh = 0; jh < 2; jh++)
#pragma unroll
                    for (int j = 0; j < 2; j++) {
                        int n = n0 + jh * 128 + wcq * 32 + j * 16 + lm;
                        D[(size_t)m * GLD + n] = f2bf(acc[ih][jh][i][j][r]);
                    }
            }
}

// ---------------------------------------------------------------------------
// m97-style bf16 MFMA NT GEMM, 128x128 tile, BK=64, global_load_lds staging,
// XOR-swizzled unpadded LDS. OUT_BF16: D bf16 [M x ldD]; else fp32 partials.
// (GEMM3 split-K fp32-partials path)
// ---------------------------------------------------------------------------
template<bool OUT_BF16>
__global__ __launch_bounds__(256)
void gemm_gll(const ushort_t* __restrict__ A, const ushort_t* __restrict__ W,
              void* __restrict__ D, int M, int N, int K, int kLen, int ldD)
{
    __shared__ __align__(16) ushort_t As[128 * 64];
    __shared__ __align__(16) ushort_t Ws[128 * 64];
    const int t    = threadIdx.x;
    const int lane = t & 63;
    const int wave = t >> 6;
    const int wr   = (wave >> 1) * 64;
    const int wc   = (wave & 1) * 64;

    const int m0 = blockIdx.y * 128;
    const int n0 = blockIdx.x * 128;
    const int kStart = blockIdx.z * kLen;

    const int srow   = lane >> 3;
    const int gchunk = (lane & 7) ^ srow;

    f32x4 acc[4][4] = {};

    for (int k0 = kStart; k0 < kStart + kLen; k0 += 64) {
#pragma unroll
        for (int it = 0; it < 4; it++) {
            const int rb = wave * 32 + it * 8;
            load_lds16(A + (size_t)(m0 + rb + srow) * K + k0 + gchunk * 8,
                       As + rb * 64);
            load_lds16(W + (size_t)(n0 + rb + srow) * K + k0 + gchunk * 8,
                       Ws + rb * 64);
        }
        __syncthreads();
#pragma unroll
        for (int kk = 0; kk < 2; kk++) {
            const int kc = kk * 4 + (lane >> 4);
            short8 af[4], bf[4];
#pragma unroll
            for (int i = 0; i < 4; i++) {
                int r = wr + i * 16 + (lane & 15);
                af[i] = *(const short8*)(As + r * 64 + ((kc ^ (r & 7)) << 3));
            }
#pragma unroll
            for (int j = 0; j < 4; j++) {
                int r = wc + j * 16 + (lane & 15);
                bf[j] = *(const short8*)(Ws + r * 64 + ((kc ^ (r & 7)) << 3));
            }
#pragma unroll
            for (int i = 0; i < 4; i++)
#pragma unroll
                for (int j = 0; j < 4; j++)
                    acc[i][j] = __builtin_amdgcn_mfma_f32_16x16x32_bf16(
                        af[i], bf[j], acc[i][j], 0, 0, 0);
        }
        __syncthreads();
    }

    if (OUT_BF16) {
        ushort_t* Dp = (ushort_t*)D;
#pragma unroll
        for (int i = 0; i < 4; i++)
#pragma unroll
            for (int r = 0; r < 4; r++) {
                int m = m0 + wr + i * 16 + ((lane >> 4) << 2) + r;
#pragma unroll
                for (int j = 0; j < 4; j++) {
                    int n = n0 + wc + j * 16 + (lane & 15);
                    Dp[(size_t)m * ldD + n] = f2bf(acc[i][j][r]);
                }
            }
    } else {
        float* Dp = (float*)D + (size_t)blockIdx.z * M * ldD;
#pragma unroll
        for (int i = 0; i < 4; i++)
#pragma unroll
            for (int r = 0; r < 4; r++) {
                int m = m0 + wr + i * 16 + ((lane >> 4) << 2) + r;
#pragma unroll
                for (int j = 0; j < 4; j++) {
                    int n = n0 + wc + j * 16 + (lane & 15);
                    Dp[(size_t)m * ldD + n] = acc[i][j][r];
                }
            }
    }
}

// out = 0.5 * (P0 + P1 + P2 + P3)
__global__ __launch_bounds__(256)
void reduce4(const float* __restrict__ P, float* __restrict__ out)
{
    int i = blockIdx.x * 256 + threadIdx.x;
    const size_t S = (size_t)M_TOT * DM / 4;
    float4 a = ((const float4*)P)[i];
    float4 b = ((const float4*)P)[i + S];
    float4 c = ((const float4*)P)[i + 2 * S];
    float4 d = ((const float4*)P)[i + 3 * S];
    float4 o;
    o.x = 0.5f * (a.x + b.x + c.x + d.x);
    o.y = 0.5f * (a.y + b.y + c.y + d.y);
    o.z = 0.5f * (a.z + b.z + c.z + d.z);
    o.w = 0.5f * (a.w + b.w + c.w + d.w);
    ((float4*)out)[i] = o;
}

// ---------------------------------------------------------------------------
// GEMM2 both-dir split-K: grid (2, M/64, 16); z = dir*8 + kz.
// P[dir][kz] = ubf[dir] * xpW[dir]^T over K-slice. 64x64 tile, N=96 masked.
// ---------------------------------------------------------------------------
#define LDSP 72

__global__ __launch_bounds__(256)
void gemm2_splitk2(const ushort_t* __restrict__ ubf, const ushort_t* __restrict__ xpWcat,
                   float* __restrict__ P)
{
    const int dir = blockIdx.z >> 3;
    const int kz  = blockIdx.z & 7;
    const ushort_t* A = ubf + (size_t)dir * M_TOT * DI;
    const ushort_t* W = xpWcat + (size_t)dir * XPD * DI;
    const int K = DI, N = XPD;

    __shared__ __align__(16) ushort_t As[64 * LDSP];
    __shared__ __align__(16) ushort_t Ws[64 * LDSP];
    const int t    = threadIdx.x;
    const int lane = t & 63;
    const int wave = t >> 6;
    const int wr   = (wave >> 1) * 32;
    const int wc   = (wave & 1) * 32;

    f32x4 acc[2][2] = {};

    const int m0 = blockIdx.y * 64;
    const int n0 = blockIdx.x * 64;
    const int kStart = kz * (DI / 8);
    const int srow = t >> 3;
    const int scol = (t & 7) << 3;

    for (int k0 = kStart; k0 < kStart + DI / 8; k0 += 64) {
        {
            int r = srow;
            short8 v = *(const short8*)(A + (size_t)(m0 + r) * K + k0 + scol);
            *(short8*)(&As[r * LDSP + scol]) = v;
            int r2 = 32 + srow;
            short8 v2 = *(const short8*)(A + (size_t)(m0 + r2) * K + k0 + scol);
            *(short8*)(&As[r2 * LDSP + scol]) = v2;
            int wn = n0 + r;
            short8 wv = {};
            if (wn < N) wv = *(const short8*)(W + (size_t)wn * K + k0 + scol);
            *(short8*)(&Ws[r * LDSP + scol]) = wv;
            int wn2 = n0 + r2;
            short8 wv2 = {};
            if (wn2 < N) wv2 = *(const short8*)(W + (size_t)wn2 * K + k0 + scol);
            *(short8*)(&Ws[r2 * LDSP + scol]) = wv2;
        }
        __syncthreads();
#pragma unroll
        for (int kk = 0; kk < 2; kk++) {
            const int kcol = kk * 32 + ((lane >> 4) << 3);
            short8 af[2], bfr[2];
#pragma unroll
            for (int i = 0; i < 2; i++)
                af[i] = *(const short8*)(&As[(wr + i * 16 + (lane & 15)) * LDSP + kcol]);
#pragma unroll
            for (int j = 0; j < 2; j++)
                bfr[j] = *(const short8*)(&Ws[(wc + j * 16 + (lane & 15)) * LDSP + kcol]);
#pragma unroll
            for (int i = 0; i < 2; i++)
#pragma unroll
                for (int j = 0; j < 2; j++)
                    acc[i][j] = __builtin_amdgcn_mfma_f32_16x16x32_bf16(
                        af[i], bfr[j], acc[i][j], 0, 0, 0);
        }
        __syncthreads();
    }

    float* Pz = P + ((size_t)dir * 8 + kz) * M_TOT * XPD;
#pragma unroll
    for (int i = 0; i < 2; i++)
#pragma unroll
        for (int r = 0; r < 4; r++) {
            int m = m0 + wr + i * 16 + ((lane >> 4) << 2) + r;
#pragma unroll
            for (int j = 0; j < 2; j++) {
                int n = n0 + wc + j * 16 + (lane & 15);
                if (n < N) Pz[(size_t)m * XPD + n] = acc[i][j][r];
            }
        }
}

// xdbl[dir] = sum of 8 partials; grid 384 (192 per dir)
__global__ __launch_bounds__(256)
void xdbl_reduce2(const float* __restrict__ P, float* __restrict__ xdbl)
{
    int bid = blockIdx.x;
    int dir = bid >= 192;
    int i = (bid - dir * 192) * 256 + threadIdx.x;   // float4 over M*XPD/4
    const size_t S = (size_t)M_TOT * XPD / 4;
    const float4* Pd = (const float4*)(P + (size_t)dir * 8 * M_TOT * XPD);
    float4 s = Pd[i];
#pragma unroll
    for (int z = 1; z < 8; z++) {
        float4 v = Pd[i + z * S];
        s.x += v.x; s.y += v.y; s.z += v.z; s.w += v.w;
    }
    ((float4*)(xdbl + (size_t)dir * M_TOT * XPD))[i] = s;
}

// ---------------------------------------------------------------------------
// delta[dir] = softplus(dt * dtW[dir]^T + dtB[dir]) -> bf16 [M x DI]
// grid (DI/64, M/64, 2); single-K-tile MFMA GEMM.
// ---------------------------------------------------------------------------
__global__ __launch_bounds__(256)
void delta_gemm2(const float* __restrict__ xdbl,
                 const float* __restrict__ dtWf, const float* __restrict__ dtWb,
                 const float* __restrict__ dtBf, const float* __restrict__ dtBb,
                 ushort_t* __restrict__ deltab)
{
    const int dir = blockIdx.z;
    const float* xd  = xdbl + (size_t)dir * M_TOT * XPD;
    const float* dtW = dir ? dtWb : dtWf;
    const float* dtB = dir ? dtBb : dtBf;
    ushort_t* delta  = deltab + (size_t)dir * M_TOT * DI;

    __shared__ __align__(16) ushort_t As[64 * LDSP];
    __shared__ __align__(16) ushort_t Ws[64 * LDSP];
    const int t    = threadIdx.x;
    const int lane = t & 63;
    const int wave = t >> 6;
    const int wr   = (wave >> 1) * 32;
    const int wc   = (wave & 1) * 32;

    const int m0 = blockIdx.y * 64;
    const int n0 = blockIdx.x * 64;
    const int srow = t >> 2;            // 0..63
    const int scol = (t & 3) << 4;      // 0,16,32,48

    {
        const float* ap = xd  + (size_t)(m0 + srow) * XPD + scol;
        const float* wp = dtW + (size_t)(n0 + srow) * RNK + scol;
        float4 a[4], w[4];
#pragma unroll
        for (int q = 0; q < 4; q++) { a[q] = ((const float4*)ap)[q]; w[q] = ((const float4*)wp)[q]; }
        __align__(16) ushort_t at[16], wt[16];
#pragma unroll
        for (int q = 0; q < 16; q++) {
            at[q] = f2bf(((const float*)a)[q]);
            wt[q] = f2bf(((const float*)w)[q]);
        }
        *(short8*)(&As[srow * LDSP + scol])     = *(const short8*)(at);
        *(short8*)(&As[srow * LDSP + scol + 8]) = *(const short8*)(at + 8);
        *(short8*)(&Ws[srow * LDSP + scol])     = *(const short8*)(wt);
        *(short8*)(&Ws[srow * LDSP + scol + 8]) = *(const short8*)(wt + 8);
    }
    __syncthreads();

    f32x4 acc[2][2] = {};
#pragma unroll
    for (int kk = 0; kk < 2; kk++) {
        const int kcol = kk * 32 + ((lane >> 4) << 3);
        short8 af[2], bfr[2];
#pragma unroll
        for (int i = 0; i < 2; i++)
            af[i] = *(const short8*)(&As[(wr + i * 16 + (lane & 15)) * LDSP + kcol]);
#pragma unroll
        for (int j = 0; j < 2; j++)
            bfr[j] = *(const short8*)(&Ws[(wc + j * 16 + (lane & 15)) * LDSP + kcol]);
#pragma unroll
        for (int i = 0; i < 2; i++)
#pragma unroll
            for (int j = 0; j < 2; j++)
                acc[i][j] = __builtin_amdgcn_mfma_f32_16x16x32_bf16(
                    af[i], bfr[j], acc[i][j], 0, 0, 0);
    }

#pragma unroll
    for (int j = 0; j < 2; j++) {
        int n = n0 + wc + j * 16 + (lane & 15);
        float bn = dtB[n];
#pragma unroll
        for (int i = 0; i < 2; i++) {
#pragma unroll
            for (int r = 0; r < 4; r++) {
                int m = m0 + wr + i * 16 + ((lane >> 4) << 2) + r;
                float v = acc[i][j][r] + bn;
                float sp = (v > 20.f) ? v : log1pf(__expf(v));
                delta[(size_t)m * DI + n] = f2bf(sp);
            }
        }
    }
}

// ---------------------------------------------------------------------------
// Depthwise conv(4) + bias + SiLU, both dirs: grid 8192 (4096 per dir).
// dir=0 causal, dir=1 anti-causal (natural order). -> ubf[dir] bf16.
// ---------------------------------------------------------------------------
__global__ __launch_bounds__(256)
void conv_silu2(const ushort_t* __restrict__ xzall,
                const float* __restrict__ convWf, const float* __restrict__ convWb,
                const float* __restrict__ convBf, const float* __restrict__ convBb,
                ushort_t* __restrict__ ubf)
{
    int bid = blockIdx.x;
    int dir = bid >> 12;                          // 4096 blocks per dir
    int idx = (bid & 4095) * 256 + threadIdx.x;   // over M_TOT*DI/4
    const float* convW = dir ? convWb : convWf;
    const float* convB = dir ? convBb : convBf;
    int di  = (idx & (DI / 4 - 1)) << 2;
    int m   = idx >> 9;
    int b   = m >> 10, l = m & (SEQ - 1);
    const ushort_t* xb = xzall + (size_t)b * SEQ * (4 * DI) + dir * (2 * DI) + di;

    float wv[4][4];
#pragma unroll
    for (int c = 0; c < 4; c++) {
        float4 w = *(const float4*)(convW + (di + c) * 4);
        wv[c][0] = w.x; wv[c][1] = w.y; wv[c][2] = w.z; wv[c][3] = w.w;
    }
    float4 cb = *(const float4*)(convB + di);
    float acc[4] = {cb.x, cb.y, cb.z, cb.w};
#pragma unroll
    for (int j = 0; j < 4; j++) {
        int srcl = dir ? (l + 3 - j) : (l - 3 + j);
        if ((unsigned)srcl < SEQ) {
            ushort4 xv = *(const ushort4*)(xb + (size_t)srcl * (4 * DI));
            acc[0] += wv[0][j] * bf2f(xv.x);
            acc[1] += wv[1][j] * bf2f(xv.y);
            acc[2] += wv[2][j] * bf2f(xv.z);
            acc[3] += wv[3][j] * bf2f(xv.w);
        }
    }
    ushort4 o;
    o.x = f2bf(acc[0] / (1.f + __expf(-acc[0])));
    o.y = f2bf(acc[1] / (1.f + __expf(-acc[1])));
    o.z = f2bf(acc[2] / (1.f + __expf(-acc[2])));
    o.w = f2bf(acc[3] / (1.f + __expf(-acc[3])));
    *(ushort4*)(ubf + (size_t)dir * M_TOT * DI + (size_t)m * DI + di) = o;
}

// ---------------------------------------------------------------------------
// Chunked selective scan, both dirs (lane = d, 16 states/lane).
// NC=64 chunks of LC=16: grid 2048 = 1024/dir.
// Within dir: dg = blk&7, c = (blk>>3)&63, b = blk>>9.
// Chunk boundary states stored bf16 (fits the dead inWcat overlay).
// ---------------------------------------------------------------------------
__global__ __launch_bounds__(256)
void scan_pass1_2(const ushort_t* __restrict__ deltab, const ushort_t* __restrict__ ubf,
                  const float* __restrict__ xdbl,
                  const float* __restrict__ Alogf, const float* __restrict__ Alogb,
                  ushort_t* __restrict__ Sb, float* __restrict__ SD)
{
    int tid = threadIdx.x, lane = tid & 63, wv = tid >> 6;
    int blk = blockIdx.x;
    int dir = blk >> 10;
    blk &= 1023;
    int dg = blk & 7;
    int bc = blk >> 3;
    int c  = bc & (NC - 1);
    int b  = bc >> 6;
    int d  = (dg * 4 + wv) * 64 + lane;
    int t0 = dir ? (SEQ - 1 - c * LC) : (c * LC);
    int rs = dir ? -1 : 1;

    const float* Alog = dir ? Alogb : Alogf;
    const ushort_t* dl_p = deltab + (size_t)dir * M_TOT * DI;
    const ushort_t* u_p  = ubf    + (size_t)dir * M_TOT * DI;
    const float*    xd   = xdbl   + (size_t)dir * M_TOT * XPD;
    ushort_t* Sbd = Sb + (size_t)dir * NC * NCH;
    float* SDd = SD + (size_t)dir * NC * B_SZ * DI;

    float ac2[NST];
#pragma unroll
    for (int q = 0; q < 4; q++) {
        float4 al = *(const float4*)(Alog + (size_t)d * NST + q * 4);
        ac2[q * 4 + 0] = -__expf(al.x) * LOG2E;
        ac2[q * 4 + 1] = -__expf(al.y) * LOG2E;
        ac2[q * 4 + 2] = -__expf(al.z) * LOG2E;
        ac2[q * 4 + 3] = -__expf(al.w) * LOG2E;
    }
    float h[NST];
#pragma unroll
    for (int n = 0; n < NST; n++) h[n] = 0.f;
    float sumD = 0.f;

#pragma unroll 4
    for (int l = 0; l < LC; l++) {
        int t = t0 + rs * l;
        size_t row = (size_t)b * SEQ + t;
        float dl = bf2f(dl_p[row * DI + d]);
        float uv = bf2f(u_p[row * DI + d]);
        const float* xr = xd + row * XPD + RNK;
        float4 Bv[4];
#pragma unroll
        for (int q = 0; q < 4; q++) Bv[q] = *(const float4*)(xr + q * 4);
        float dlu = dl * uv;
        sumD += dl;
#pragma unroll
        for (int n = 0; n < NST; n++) {
            float dA = EXP2F(dl * ac2[n]);
            h[n] = h[n] * dA + dlu * ((const float*)Bv)[n];
        }
    }

    size_t o = (size_t)c * NCH + ((size_t)b * DI + d) * NST;
#pragma unroll
    for (int q = 0; q < 4; q++) {
        ushort4 pk;
        pk.x = f2bf(h[q * 4 + 0]);
        pk.y = f2bf(h[q * 4 + 1]);
        pk.z = f2bf(h[q * 4 + 2]);
        pk.w = f2bf(h[q * 4 + 3]);
        *(ushort4*)(Sbd + o + q * 4) = pk;
    }
    SDd[(size_t)c * (B_SZ * DI) + b * DI + d] = sumD;
}

__global__ __launch_bounds__(256)
void scan_combine2(ushort_t* __restrict__ Sb, const float* __restrict__ SD,
                   const float* __restrict__ Alogf, const float* __restrict__ Alogb)
{
    int gid = blockIdx.x * 256 + threadIdx.x;   // 0 .. 2*NCH-1
    int dir = gid >= NCH;
    int i = gid - dir * NCH;
    int n = i & 15;
    int d = (i >> 4) & (DI - 1);
    int b = i >> 15;
    const float* Alog = dir ? Alogb : Alogf;
    ushort_t* Sbd = Sb + (size_t)dir * NC * NCH;
    const float* SDd = SD + (size_t)dir * NC * B_SZ * DI;
    float ac2 = -__expf(Alog[(size_t)d * NST + n]) * LOG2E;
    float h = 0.f;
#pragma unroll
    for (int c = 0; c < NC; c++) {
        float s = bf2f(Sbd[(size_t)c * NCH + i]);
        float p = EXP2F(ac2 * SDd[(size_t)c * (B_SZ * DI) + b * DI + d]);
        Sbd[(size_t)c * NCH + i] = f2bf(h);
        h = s + p * h;
    }
}

__global__ __launch_bounds__(256)
void scan_pass2_2(const ushort_t* __restrict__ deltab, const ushort_t* __restrict__ ubf,
                  const float* __restrict__ xdbl, const ushort_t* __restrict__ xzall,
                  const float* __restrict__ Alogf, const float* __restrict__ Alogb,
                  const float* __restrict__ Dpf, const float* __restrict__ Dpb,
                  const ushort_t* __restrict__ Hinit, ushort_t* __restrict__ ybf)
{
    int tid = threadIdx.x, lane = tid & 63, wv = tid >> 6;
    int blk = blockIdx.x;
    int dir = blk >> 10;
    blk &= 1023;
    int dg = blk & 7;
    int bc = blk >> 3;
    int c  = bc & (NC - 1);
    int b  = bc >> 6;
    int d  = (dg * 4 + wv) * 64 + lane;
    int t0 = dir ? (SEQ - 1 - c * LC) : (c * LC);
    int rs = dir ? -1 : 1;

    const float* Alog = dir ? Alogb : Alogf;
    const float* Dpp  = dir ? Dpb : Dpf;
    const ushort_t* dl_p = deltab + (size_t)dir * M_TOT * DI;
    const ushort_t* u_p  = ubf    + (size_t)dir * M_TOT * DI;
    const float*    xd   = xdbl   + (size_t)dir * M_TOT * XPD;
    const ushort_t* Hin  = Hinit  + (size_t)dir * NC * NCH;

    float ac2[NST];
#pragma unroll
    for (int q = 0; q < 4; q++) {
        float4 al = *(const float4*)(Alog + (size_t)d * NST + q * 4);
        ac2[q * 4 + 0] = -__expf(al.x) * LOG2E;
        ac2[q * 4 + 1] = -__expf(al.y) * LOG2E;
        ac2[q * 4 + 2] = -__expf(al.z) * LOG2E;
        ac2[q * 4 + 3] = -__expf(al.w) * LOG2E;
    }
    float dp = Dpp[d];
    float h[NST];
    {
        size_t o = (size_t)c * NCH + ((size_t)b * DI + d) * NST;
#pragma unroll
        for (int q = 0; q < 4; q++) {
            ushort4 hv = *(const ushort4*)(Hin + o + q * 4);
            h[q*4]   = bf2f(hv.x);
            h[q*4+1] = bf2f(hv.y);
            h[q*4+2] = bf2f(hv.z);
            h[q*4+3] = bf2f(hv.w);
        }
    }

#pragma unroll 4
    for (int l = 0; l < LC; l++) {
        int t = t0 + rs * l;
        size_t row = (size_t)b * SEQ + t;
        float dl = bf2f(dl_p[row * DI + d]);
        float uv = bf2f(u_p[row * DI + d]);
        const float* xr = xd + row * XPD + RNK;
        float4 Bv[4], Cv[4];
#pragma unroll
        for (int q = 0; q < 4; q++) {
            Bv[q] = *(const float4*)(xr + q * 4);
            Cv[q] = *(const float4*)(xr + NST + q * 4);
        }
        float dlu = dl * uv;
        float y = 0.f;
#pragma unroll
        for (int n = 0; n < NST; n++) {
            float dA = EXP2F(dl * ac2[n]);
            h[n] = h[n] * dA + dlu * ((const float*)Bv)[n];
            y += h[n] * ((const float*)Cv)[n];
        }
        float z = bf2f(xzall[row * (4 * DI) + dir * (2 * DI) + DI + d]);
        float yv = (y + uv * dp) * (z / (1.f + __expf(-z)));
        ybf[row * (2 * DI) + dir * DI + d] = f2bf(yv);
    }
}

// ---------------------------------------------------------------------------
extern "C" void kernel_launch(void* const* d_in, const int* in_sizes, int n_in,
                              void* d_out, int out_size, void* d_ws, size_t ws_size,
                              hipStream_t stream)
{
    char* wsb = (char*)d_ws;

    // layout (bytes), total 115,605,504:
    ushort_t* xzall  = (ushort_t*)wsb;                 // 33,554,432 [M x 8192] bf16
    ushort_t* ybf    = (ushort_t*)(wsb + 33554432);    // 16,777,216 [M x 2*DI] bf16
    ushort_t* inWcat = (ushort_t*)(wsb + 50331648);    // 16,777,216
    ushort_t* outWcat= (ushort_t*)(wsb + 67108864);    //  8,388,608 [DM x 2*DI] bf16
    ushort_t* xbf    = (ushort_t*)(wsb + 75497472);    //  4,194,304 [M x DM] bf16
    ushort_t* xpWcat = (ushort_t*)(wsb + 79691776);    //    786,432 [2][XPD x DI] bf16
    ushort_t* ubf    = (ushort_t*)(wsb + 80478208);    // 16,777,216 [2][M x DI] bf16
    ushort_t* deltab = (ushort_t*)(wsb + 97255424);    // 16,777,216 [2][M x DI] bf16
    float*    xdbl   = (float*)(wsb + 114032640);      //  1,572,864 [2][M x XPD] fp32

    // overlays (dead regions):
    ushort_t* Sb   = (ushort_t*)inWcat;                // 16,777,216 [2][NC=64 x NCH] bf16 (after GEMM1)
    float* SD    = (float*)xbf;                        //  2,097,152 [2][NC x B*DI]   (after GEMM1)
    float* part2 = (float*)deltab;                     // 12,582,912 [2][8 x M x XPD] (pre-delta)
    float* part4 = (float*)xzall;                      // 33,554,432 (after scans)

    float* out = (float*)d_out;
    dim3 blk(256);

    // 1. prologue conversions (single dispatch)
    convert_all<<<14720, blk, 0, stream>>>(
        (const float*)d_in[0], (const float*)d_in[1], (const float*)d_in[10],
        (const float*)d_in[9], (const float*)d_in[18],
        (const float*)d_in[4], (const float*)d_in[13],
        xbf, inWcat, outWcat, xpWcat);

    // 2. xzall = x * [inW_f; inW_b]^T   [2048 x 8192], K=1024, bf16 out
    //    256x256 8-phase counted-vmcnt schedule (grid 32x8 = 256 blocks)
    gemm256_bf16<<<dim3(8192 / 256, M_TOT / 256), dim3(512), 0, stream>>>(
        xbf, inWcat, xzall);

    // 3. u = silu(conv(xi)), both dirs (4096 blocks per dir)
    conv_silu2<<<8192, blk, 0, stream>>>(xzall,
        (const float*)d_in[2], (const float*)d_in[11],
        (const float*)d_in[3], (const float*)d_in[12], ubf);

    // 4. xdbl partials, both dirs, split-K=8
    gemm2_splitk2<<<dim3(2, M_TOT / 64, 16), blk, 0, stream>>>(ubf, xpWcat, part2);

    // 5. xdbl = sum partials, both dirs
    xdbl_reduce2<<<384, blk, 0, stream>>>(part2, xdbl);

    // 6. delta = softplus(dt*dtW^T + dtB) -> bf16, both dirs
    delta_gemm2<<<dim3(DI / 64, M_TOT / 64, 2), blk, 0, stream>>>(
        xdbl, (const float*)d_in[5], (const float*)d_in[14],
        (const float*)d_in[6], (const float*)d_in[15], deltab);

    // 7-9. chunked exact scan (NC=64 chunks of LC=16), both dirs
    scan_pass1_2<<<2048, blk, 0, stream>>>(deltab, ubf, xdbl,
        (const float*)d_in[7], (const float*)d_in[16], Sb, SD);
    scan_combine2<<<2 * NCH / 256, blk, 0, stream>>>(Sb, SD,
        (const float*)d_in[7], (const float*)d_in[16]);
    scan_pass2_2<<<2048, blk, 0, stream>>>(deltab, ubf, xdbl, xzall,
        (const float*)d_in[7], (const float*)d_in[16],
        (const float*)d_in[8], (const float*)d_in[17], Sb, ybf);

    // 10. out = 0.5 * [y_f | y_b] * [outW_f | outW_b]^T : K=4096, splitK=4
    gemm_gll<false><<<dim3(DM / 128, M_TOT / 128, 4), blk, 0, stream>>>(
        ybf, outWcat, part4, M_TOT, DM, 2 * DI, DI / 2, DM);

    // 11. final reduce
    reduce4<<<(M_TOT * DM / 4) / 256, blk, 0, stream>>>(part4, out);
}